// Round 8
// baseline (477.658 us; speedup 1.0000x reference)
//
#include <hip/hip_runtime.h>
#include <hip/hip_bf16.h>

#define N_EMBD 1024
#define N_HEAD 16
#define HEADSZ 64
#define BATCH  2
#define SEQ    2048
#define ROWS   (BATCH*SEQ)   /* 4096 */

typedef __attribute__((ext_vector_type(8))) short bf16x8;
typedef __attribute__((ext_vector_type(4))) float f32x4;

__device__ __forceinline__ short f2bs(float v){
    union { __hip_bfloat16 b; short s; } u; u.b = __float2bfloat16(v); return u.s;
}
__device__ __forceinline__ short scale8th(short s){   // exact: *0.125 (pow2)
    union { unsigned i; float f; } u; u.i = ((unsigned)(unsigned short)s) << 16;
    return f2bs(u.f * 0.125f);
}
__device__ __forceinline__ void gload16(const short* g, short* l){
    __builtin_amdgcn_global_load_lds(
        (const __attribute__((address_space(1))) unsigned int*)g,
        (__attribute__((address_space(3))) unsigned int*)l, 16, 0, 0);
}

// ---------------------------------------------------------------------------
// Transpose + f32->bf16 convert: out[j][i] = in[i][j]; in is [R][Cc] f32.
// ---------------------------------------------------------------------------
__global__ __launch_bounds__(256) void tr_cvt(const float* __restrict__ in,
                                              short* __restrict__ out,
                                              int R, int Cc,
                                              size_t in_z, size_t out_z)
{
    __shared__ float t[32][33];
    const int tx = threadIdx.x & 31, ty = threadIdx.x >> 5;
    const int j0 = blockIdx.x * 32, i0 = blockIdx.y * 32;
    const float* ip = in + (size_t)blockIdx.z * in_z;
    short* op = out + (size_t)blockIdx.z * out_z;
#pragma unroll
    for (int p = 0; p < 4; ++p)
        t[ty + p * 8][tx] = ip[(size_t)(i0 + ty + p * 8) * Cc + j0 + tx];
    __syncthreads();
#pragma unroll
    for (int p = 0; p < 4; ++p)
        op[(size_t)(j0 + ty + p * 8) * R + i0 + tx] = f2bs(t[tx][ty + p * 8]);
}

// Fused Wq/Wk/Wv transpose: z = which*16 + head; per-head [1024][64] -> [64][1024]
__global__ __launch_bounds__(256) void tr3_cvt(const float* __restrict__ Wq,
                                               const float* __restrict__ Wk,
                                               const float* __restrict__ Wv,
                                               short* __restrict__ w2t)
{
    __shared__ float t[32][33];
    const int tx = threadIdx.x & 31, ty = threadIdx.x >> 5;
    const int which = blockIdx.z >> 4, head = blockIdx.z & 15;
    const int j0 = blockIdx.x * 32, i0 = blockIdx.y * 32;
    const float* ip = (which == 0 ? Wq : which == 1 ? Wk : Wv) + (size_t)head * 65536;
    short* op = w2t + (size_t)which * 1048576 + (size_t)head * 65536;
#pragma unroll
    for (int p = 0; p < 4; ++p)
        t[ty + p * 8][tx] = ip[(size_t)(i0 + ty + p * 8) * 64 + j0 + tx];
    __syncthreads();
#pragma unroll
    for (int p = 0; p < 4; ++p)
        op[(size_t)(j0 + ty + p * 8) * 1024 + i0 + tx] = f2bs(t[tx][ty + p * 8]);
}

// ---------------------------------------------------------------------------
// bf16 transpose of the V slice of qkv: vt[c][token] = qkv[token][2048+c]
// ---------------------------------------------------------------------------
__global__ __launch_bounds__(256) void vt_tr(const short* __restrict__ qkv,
                                             short* __restrict__ vt)
{
    __shared__ short t[64][65];
    const int tid = threadIdx.x;
    const int sr = tid >> 2, sc = (tid & 3) * 16;
    const int col0 = blockIdx.x * 64, tok0 = blockIdx.y * 64;
    const short* ip = qkv + (size_t)(tok0 + sr) * 3072 + 2048 + col0 + sc;
    bf16x8 v0 = *(const bf16x8*)ip;
    bf16x8 v1 = *(const bf16x8*)(ip + 8);
#pragma unroll
    for (int i = 0; i < 8; ++i) { t[sr][sc + i] = v0[i]; t[sr][sc + 8 + i] = v1[i]; }
    __syncthreads();
    bf16x8 a, bq;
#pragma unroll
    for (int i = 0; i < 8; ++i) { a[i] = t[sc + i][sr]; bq[i] = t[sc + 8 + i][sr]; }
    short* op = vt + (size_t)(col0 + sr) * 4096 + tok0 + sc;
    *(bf16x8*)op = a;
    *(bf16x8*)(op + 8) = bq;
}

// ---------------------------------------------------------------------------
// LayerNorm (LN1): one block per row of 1024, float4 loads, bf16 output
// ---------------------------------------------------------------------------
__global__ __launch_bounds__(256) void ln_k(const float* __restrict__ x,
                                            const float* __restrict__ g,
                                            const float* __restrict__ bta,
                                            short* __restrict__ out)
{
    const int row = blockIdx.x;
    const int tid = threadIdx.x;
    const float* xr = x + (size_t)row * N_EMBD;
    float4 v = *(const float4*)(xr + tid * 4);
    float s  = v.x + v.y + v.z + v.w;
    float s2 = v.x * v.x + v.y * v.y + v.z * v.z + v.w * v.w;
#pragma unroll
    for (int off = 32; off; off >>= 1) {
        s  += __shfl_xor(s,  off, 64);
        s2 += __shfl_xor(s2, off, 64);
    }
    __shared__ float rs[4], rs2[4];
    const int wave = tid >> 6, lane = tid & 63;
    if (lane == 0) { rs[wave] = s; rs2[wave] = s2; }
    __syncthreads();
    s  = rs[0] + rs[1] + rs[2] + rs[3];
    s2 = rs2[0] + rs2[1] + rs2[2] + rs2[3];
    const float mean = s * (1.f / N_EMBD);
    const float var  = s2 * (1.f / N_EMBD) - mean * mean;
    const float rsig = rsqrtf(var + 1e-5f);
    float4 gv = *(const float4*)(g + tid * 4);
    float4 bv = *(const float4*)(bta + tid * 4);
    short4 o;
    o.x = f2bs((v.x - mean) * rsig * gv.x + bv.x);
    o.y = f2bs((v.y - mean) * rsig * gv.y + bv.y);
    o.z = f2bs((v.z - mean) * rsig * gv.z + bv.z);
    o.w = f2bs((v.w - mean) * rsig * gv.w + bv.w);
    *(short4*)(out + (size_t)row * N_EMBD + tid * 4) = o;
}

// ---------------------------------------------------------------------------
// Fused proj-finalize + LN2: x2 = p0+p1+bias+x (write f32); h2 = LN(x2) bf16.
// One block per row.
// ---------------------------------------------------------------------------
__global__ __launch_bounds__(256) void pln_fin(const float* __restrict__ p0,
                                               const float* __restrict__ p1,
                                               const float* __restrict__ bias,
                                               const float* __restrict__ x,
                                               const float* __restrict__ g,
                                               const float* __restrict__ bta,
                                               float* __restrict__ x2,
                                               short* __restrict__ h2)
{
    const int row = blockIdx.x, tid = threadIdx.x;
    const size_t base = (size_t)row * N_EMBD + tid * 4;
    float4 a  = *(const float4*)(p0 + base);
    float4 c  = *(const float4*)(p1 + base);
    float4 xx = *(const float4*)(x + base);
    float4 bb = *(const float4*)(bias + tid * 4);
    float4 v;
    v.x = a.x + c.x + xx.x + bb.x;
    v.y = a.y + c.y + xx.y + bb.y;
    v.z = a.z + c.z + xx.z + bb.z;
    v.w = a.w + c.w + xx.w + bb.w;
    *(float4*)(x2 + base) = v;
    float s  = v.x + v.y + v.z + v.w;
    float s2 = v.x * v.x + v.y * v.y + v.z * v.z + v.w * v.w;
#pragma unroll
    for (int off = 32; off; off >>= 1) {
        s  += __shfl_xor(s,  off, 64);
        s2 += __shfl_xor(s2, off, 64);
    }
    __shared__ float rs[4], rs2[4];
    const int wave = tid >> 6, lane = tid & 63;
    if (lane == 0) { rs[wave] = s; rs2[wave] = s2; }
    __syncthreads();
    s  = rs[0] + rs[1] + rs[2] + rs[3];
    s2 = rs2[0] + rs2[1] + rs2[2] + rs2[3];
    const float mean = s * (1.f / N_EMBD);
    const float var  = s2 * (1.f / N_EMBD) - mean * mean;
    const float rsig = rsqrtf(var + 1e-5f);
    float4 gv = *(const float4*)(g + tid * 4);
    float4 bv = *(const float4*)(bta + tid * 4);
    short4 o;
    o.x = f2bs((v.x - mean) * rsig * gv.x + bv.x);
    o.y = f2bs((v.y - mean) * rsig * gv.y + bv.y);
    o.z = f2bs((v.z - mean) * rsig * gv.z + bv.z);
    o.w = f2bs((v.w - mean) * rsig * gv.w + bv.w);
    *(short4*)(h2 + base) = o;
}

// ---------------------------------------------------------------------------
// MFMA GEMM, bank-conflict-swizzled LDS: 16-B chunk c of row r stored at
// c ^ ((r>>1)&3) (4 chunks/row). Swizzle applied on the GLOBAL address side
// of global_load_lds (LDS dest stays linear); frag reads XOR the same term
// -> 2 lanes/bank (free). Split-K via kz (z picks outf/outf2, raw partials).
// ---------------------------------------------------------------------------
__global__ __launch_bounds__(256) void mfma_gemm(
    const short* __restrict__ A,    // [M][K] bf16
    const short* __restrict__ Bt,   // [N][K] bf16
    const float* __restrict__ bias,
    const float* __restrict__ resid,
    float* __restrict__ outf,
    float* __restrict__ outf2,
    short* __restrict__ outb,
    int M, int N, int K, int kz, int relu)
{
    __shared__ __align__(16) short As[128 * 32];
    __shared__ __align__(16) short Bs[128 * 32];
    const int tid  = threadIdx.x;
    const int lane = tid & 63, w = tid >> 6;
    const int quad = lane >> 4, l16 = lane & 15;
    const int row0 = blockIdx.y * 128, col0 = blockIdx.x * 128;
    const int wm = (w >> 1) * 64, wn = (w & 1) * 64;
    const int koff = blockIdx.z * kz;
    const int kend = kz ? kz : K;

    f32x4 acc[4][4];
#pragma unroll
    for (int i = 0; i < 4; ++i)
#pragma unroll
        for (int j = 0; j < 4; ++j)
            acc[i][j] = f32x4{0.f, 0.f, 0.f, 0.f};

    const int c0  = w * 128 + lane;
    const int c1  = c0 + 64;
    const int ar0 = c0 >> 2, ak0 = (((c0 & 3) ^ ((ar0 >> 1) & 3))) * 8; // swizzled
    const int ar1 = c1 >> 2, ak1 = (((c1 & 3) ^ ((ar1 >> 1) & 3))) * 8;
    const short* aG0 = A  + (size_t)(row0 + ar0) * K + koff + ak0;
    const short* aG1 = A  + (size_t)(row0 + ar1) * K + koff + ak1;
    const short* bG0 = Bt + (size_t)(col0 + ar0) * K + koff + ak0;
    const short* bG1 = Bt + (size_t)(col0 + ar1) * K + koff + ak1;
    short* aL0 = As + (size_t)w * 1024;
    short* aL1 = aL0 + 512;
    short* bL0 = Bs + (size_t)w * 1024;
    short* bL1 = bL0 + 512;

    const int gsw = (quad ^ ((l16 >> 1) & 3)) * 8;   // swizzled frag chunk

    for (int k0 = 0; k0 < kend; k0 += 32) {
        __syncthreads();
        gload16(aG0 + k0, aL0);
        gload16(aG1 + k0, aL1);
        gload16(bG0 + k0, bL0);
        gload16(bG1 + k0, bL1);
        asm volatile("s_waitcnt vmcnt(0)" ::: "memory");
        __syncthreads();

        bf16x8 af[4], bfr[4];
#pragma unroll
        for (int i = 0; i < 4; ++i)
            af[i]  = *(const bf16x8*)(As + (wm + i * 16 + l16) * 32 + gsw);
#pragma unroll
        for (int j = 0; j < 4; ++j)
            bfr[j] = *(const bf16x8*)(Bs + (wn + j * 16 + l16) * 32 + gsw);
#pragma unroll
        for (int i = 0; i < 4; ++i)
#pragma unroll
            for (int j = 0; j < 4; ++j)
                acc[i][j] = __builtin_amdgcn_mfma_f32_16x16x32_bf16(
                    af[i], bfr[j], acc[i][j], 0, 0, 0);
    }

    float* of = blockIdx.z ? outf2 : outf;
#pragma unroll
    for (int i = 0; i < 4; ++i) {
        const int rbase = row0 + wm + i * 16 + quad * 4;
#pragma unroll
        for (int j = 0; j < 4; ++j) {
            const int c = col0 + wn + j * 16 + l16;
            const float bv = bias ? bias[c] : 0.f;
#pragma unroll
            for (int r = 0; r < 4; ++r) {
                float v = acc[i][j][r] + bv;
                if (relu) v = fmaxf(v, 0.f);
                const size_t idx = (size_t)(rbase + r) * N + c;
                if (resid) v += resid[idx];
                if (outb) outb[idx] = f2bs(v);
                else      of[idx] = v;
            }
        }
    }
}

// ---------------------------------------------------------------------------
// FF2 finalize: out = p0 + out + bias + x2   (all f32, N=1024 bias period)
// ---------------------------------------------------------------------------
__global__ __launch_bounds__(256) void ff2_fin(const float* __restrict__ p0,
                                               const float* __restrict__ bias,
                                               const float* __restrict__ x2,
                                               float* __restrict__ out)
{
    const size_t i = ((size_t)blockIdx.x * 256 + threadIdx.x) * 4;
    float4 a = *(const float4*)(p0 + i);
    float4 b = *(const float4*)(out + i);
    float4 r = *(const float4*)(x2 + i);
    float4 bb = *(const float4*)(bias + (i & 1023));
    float4 o;
    o.x = a.x + b.x + r.x + bb.x;
    o.y = a.y + b.y + r.y + bb.y;
    o.z = a.z + b.z + r.z + bb.z;
    o.w = a.w + b.w + r.w + bb.w;
    *(float4*)(out + i) = o;
}

// ---------------------------------------------------------------------------
// MFMA flash attention: 4 waves / 64 q-rows (good K/V L2 reuse), K/V double-
// buffered with 1-tile prefetch, ONE barrier per tile, XOR-swizzled LDS
// (8 chunks/row: chunk c of row r at c^(r&7) -> conflict-free b128 reads).
// Pair {bx, 31-bx} -> uniform 33 key-tiles/block. LDS 48.8 KB.
// ---------------------------------------------------------------------------
__global__ __launch_bounds__(256) void attn_k(const short* __restrict__ qkv,
                                              const short* __restrict__ vt,
                                              short* __restrict__ att)
{
    __shared__ __align__(16) short Ks[2][64 * 64];   // [s][d] swizzled
    __shared__ __align__(16) short Vs[2][64 * 64];   // [d][s] swizzled
    __shared__ __align__(16) short Ps[64 * 72];      // [q][s], stride 72
    const int tid  = threadIdx.x;
    const int lane = tid & 63, w = tid >> 6;         // w in 0..3
    const int quad = lane >> 4, l16 = lane & 15;
    const int bh = blockIdx.y, b = bh >> 4, head = bh & 15;

    const int srow = lane >> 3;                       // 0..7
    const int sw   = ((lane & 7) ^ srow) * 8;         // staging swizzle (shorts)
    const int cidx = (quad ^ (l16 & 7)) * 8;          // frag-read swizzle

#pragma unroll
    for (int pass = 0; pass < 2; ++pass) {
        const int qt = pass == 0 ? (int)blockIdx.x : 31 - (int)blockIdx.x;
        const int t0 = qt * 64;
        const int ntiles = qt + 1;

        // Q fragments (registers), scale folded in (exact pow2)
        const short* qp = qkv + (size_t)(b * SEQ + t0 + w * 16 + l16) * 3072
                          + head * 64 + quad * 8;
        bf16x8 qf0 = *(const bf16x8*)qp;
        bf16x8 qf1 = *(const bf16x8*)(qp + 32);
#pragma unroll
        for (int i = 0; i < 8; ++i) { qf0[i] = scale8th(qf0[i]); qf1[i] = scale8th(qf1[i]); }

        float mrow[4], lrow[4];
        f32x4 O[4];
#pragma unroll
        for (int r = 0; r < 4; ++r) { mrow[r] = -INFINITY; lrow[r] = 0.f; }
#pragma unroll
        for (int jn = 0; jn < 4; ++jn) O[jn] = f32x4{0.f, 0.f, 0.f, 0.f};

        // guard: previous pass fully done before overwriting buf0
        asm volatile("s_waitcnt vmcnt(0) lgkmcnt(0)\n\ts_barrier" ::: "memory");
        {   // prefetch tile 0 -> buffer 0 (wave w: K rows / V d-rows [w*16,+16))
            const short* kg = qkv + (size_t)(b * SEQ + w * 16 + srow) * 3072
                              + 1024 + head * 64 + sw;
            const short* vg = vt + (size_t)(head * 64 + w * 16 + srow) * 4096
                              + b * SEQ + sw;
            short* kL = Ks[0] + w * 1024;
            short* vL = Vs[0] + w * 1024;
            gload16(kg, kL); gload16(kg + (size_t)8 * 3072, kL + 512);
            gload16(vg, vL); gload16(vg + (size_t)8 * 4096, vL + 512);
        }

        for (int kt = 0; kt < ntiles; ++kt) {
            const int cur = kt & 1;
            // prefetched tile kt landed (all waves), prev compute done
            asm volatile("s_waitcnt vmcnt(0) lgkmcnt(0)\n\ts_barrier" ::: "memory");
            if (kt + 1 < ntiles) {
                const int s1 = (kt + 1) * 64;
                const short* kg = qkv + (size_t)(b * SEQ + s1 + w * 16 + srow) * 3072
                                  + 1024 + head * 64 + sw;
                const short* vg = vt + (size_t)(head * 64 + w * 16 + srow) * 4096
                                  + b * SEQ + s1 + sw;
                short* kL = Ks[cur ^ 1] + w * 1024;
                short* vL = Vs[cur ^ 1] + w * 1024;
                gload16(kg, kL); gload16(kg + (size_t)8 * 3072, kL + 512);
                gload16(vg, vL); gload16(vg + (size_t)8 * 4096, vL + 512);
            }

            // --- S = Q.K^T ---
            f32x4 S[4];
            const short* Kb = Ks[cur];
#pragma unroll
            for (int jn = 0; jn < 4; ++jn) {
                S[jn] = f32x4{0.f, 0.f, 0.f, 0.f};
                const short* kp = Kb + (jn * 16 + l16) * 64;
                bf16x8 b0 = *(const bf16x8*)(kp + cidx);
                bf16x8 b1 = *(const bf16x8*)(kp + (cidx ^ 32));
                S[jn] = __builtin_amdgcn_mfma_f32_16x16x32_bf16(qf0, b0, S[jn], 0, 0, 0);
                S[jn] = __builtin_amdgcn_mfma_f32_16x16x32_bf16(qf1, b1, S[jn], 0, 0, 0);
            }

            // --- softmax (C/D layout: row=quad*4+r, col=jn*16+l16) ---
            float Sv[4][4];
            const int tq = t0 + w * 16 + quad * 4;
            const int s0 = kt * 64;
#pragma unroll
            for (int jn = 0; jn < 4; ++jn)
#pragma unroll
                for (int r = 0; r < 4; ++r)
                    Sv[jn][r] = S[jn][r];
            if (kt == ntiles - 1) {   // diagonal tile
#pragma unroll
                for (int jn = 0; jn < 4; ++jn)
#pragma unroll
                    for (int r = 0; r < 4; ++r)
                        if (s0 + jn * 16 + l16 > tq + r) Sv[jn][r] = -INFINITY;
            }
#pragma unroll
            for (int r = 0; r < 4; ++r) {
                float rm = fmaxf(fmaxf(Sv[0][r], Sv[1][r]), fmaxf(Sv[2][r], Sv[3][r]));
#pragma unroll
                for (int off = 8; off; off >>= 1) rm = fmaxf(rm, __shfl_xor(rm, off, 64));
                const float mn    = fmaxf(mrow[r], rm);
                const float alpha = __expf(mrow[r] - mn);   // 0 on first tile
                float ps = 0.f;
#pragma unroll
                for (int jn = 0; jn < 4; ++jn) {
                    Sv[jn][r] = __expf(Sv[jn][r] - mn);
                    ps += Sv[jn][r];
                }
#pragma unroll
                for (int off = 8; off; off >>= 1) ps += __shfl_xor(ps, off, 64);
                lrow[r] = lrow[r] * alpha + ps;
                mrow[r] = mn;
#pragma unroll
                for (int jn = 0; jn < 4; ++jn) O[jn][r] *= alpha;
            }

            // --- P -> LDS (wave-local rows; lgkm wait only) ---
#pragma unroll
            for (int jn = 0; jn < 4; ++jn)
#pragma unroll
                for (int r = 0; r < 4; ++r)
                    Ps[(w * 16 + quad * 4 + r) * 72 + jn * 16 + l16] = f2bs(Sv[jn][r]);
            asm volatile("s_waitcnt lgkmcnt(0)" ::: "memory");

            // --- O += P.V ---
            const short* pp = Ps + (w * 16 + l16) * 72 + quad * 8;
            bf16x8 pf0 = *(const bf16x8*)pp;
            bf16x8 pf1 = *(const bf16x8*)(pp + 32);
            const short* Vb = Vs[cur];
#pragma unroll
            for (int jn = 0; jn < 4; ++jn) {
                const short* vp = Vb + (jn * 16 + l16) * 64;
                bf16x8 v0 = *(const bf16x8*)(vp + cidx);
                bf16x8 v1 = *(const bf16x8*)(vp + (cidx ^ 32));
                O[jn] = __builtin_amdgcn_mfma_f32_16x16x32_bf16(pf0, v0, O[jn], 0, 0, 0);
                O[jn] = __builtin_amdgcn_mfma_f32_16x16x32_bf16(pf1, v1, O[jn], 0, 0, 0);
            }
        }

        // --- write O/l ---
#pragma unroll
        for (int r = 0; r < 4; ++r) {
            const float inv = 1.f / lrow[r];
            const size_t rowoff = (size_t)(b * SEQ + t0 + w * 16 + quad * 4 + r) * N_EMBD
                                  + head * 64 + l16;
#pragma unroll
            for (int jn = 0; jn < 4; ++jn)
                att[rowoff + jn * 16] = f2bs(O[jn][r] * inv);
        }
    }
}

// ---------------------------------------------------------------------------
extern "C" void kernel_launch(void* const* d_in, const int* in_sizes, int n_in,
                              void* d_out, int out_size, void* d_ws, size_t ws_size,
                              hipStream_t stream)
{
    const float* x     = (const float*)d_in[0];
    const float* Wq    = (const float*)d_in[1];
    const float* Wk    = (const float*)d_in[2];
    const float* Wv    = (const float*)d_in[3];
    const float* Wproj = (const float*)d_in[4];
    const float* bproj = (const float*)d_in[5];
    const float* g1    = (const float*)d_in[6];
    const float* b1    = (const float*)d_in[7];
    const float* g2    = (const float*)d_in[8];
    const float* b2    = (const float*)d_in[9];
    const float* Wff1  = (const float*)d_in[10];
    const float* bff1  = (const float*)d_in[11];
    const float* Wff2  = (const float*)d_in[12];
    const float* bff2  = (const float*)d_in[13];
    float* out = (float*)d_out;

    char* ws = (char*)d_ws;
    short* w2t  = (short*)(ws + 0);          // [3072][1024] bf16 (dead after QKV)
    short* wpt  = (short*)(ws + 6291456);    // [1024][1024] (dead after proj)
    short* wf1t = (short*)(ws + 8388608);    // [4096][1024] (dead after FF1)
    short* wf2t = (short*)(ws + 16777216);   // [1024][4096]
    short* h    = (short*)(ws + 25165824);   // [4096][1024] (=h2)
    short* qkv  = (short*)(ws + 33554432);   // [4096][3072] (dead after attn)
    short* vt   = (short*)(ws + 58720256);   // [1024][4096] (dead after attn)
    short* att  = (short*)(ws + 67108864);   // [4096][1024]
    float* x2   = (float*)(ws + 75497472);   // [4096][1024] f32
    short* h2   = h;
    // proj split-K partials alias dead qkv+vt (16.78 MB each, end exactly at att)
    float* p0p  = (float*)(ws + 33554432);
    float* p1p  = (float*)(ws + 50331648);
    short* ff   = qkv;                       // [4096][4096] (p0p/p1p dead by FF1)
    float* p0f  = (float*)(ws + 0);          // FF2 partial over w2t+wpt+wf1t (dead)

    tr3_cvt<<<dim3(2, 32, 48),  256, 0, stream>>>(Wq, Wk, Wv, w2t);
    tr_cvt<<<dim3(32, 32, 1),  256, 0, stream>>>(Wproj, wpt,  1024, 1024, 0, 0);
    tr_cvt<<<dim3(128, 32, 1), 256, 0, stream>>>(Wff1, wf1t,  1024, 4096, 0, 0);
    tr_cvt<<<dim3(32, 128, 1), 256, 0, stream>>>(Wff2, wf2t,  4096, 1024, 0, 0);

    ln_k<<<ROWS, 256, 0, stream>>>(x, g1, b1, h);
    // QKV: [4096,1024] x [1024,3072] -> bf16 qkv
    mfma_gemm<<<dim3(3072 / 128, ROWS / 128), 256, 0, stream>>>(
        h, w2t, nullptr, nullptr, nullptr, nullptr, qkv, ROWS, 3072, N_EMBD, 0, 0);
    vt_tr<<<dim3(16, 64), 256, 0, stream>>>(qkv, vt);
    attn_k<<<dim3(32, BATCH * N_HEAD), 256, 0, stream>>>(qkv, vt, att);
    // proj split-K=2 -> raw partials p0p/p1p (512 blocks)
    mfma_gemm<<<dim3(N_EMBD / 128, ROWS / 128, 2), 256, 0, stream>>>(
        att, wpt, nullptr, nullptr, p0p, p1p, nullptr, ROWS, N_EMBD, N_EMBD, 512, 0);
    // fused proj-epilogue + LN2: x2 = p0p+p1p+bproj+x ; h2 = LN(x2)
    pln_fin<<<ROWS, 256, 0, stream>>>(p0p, p1p, bproj, x, g2, b2, x2, h2);
    // FF1 + bias + relu -> bf16 ff
    mfma_gemm<<<dim3(4096 / 128, ROWS / 128), 256, 0, stream>>>(
        h2, wf1t, bff1, nullptr, nullptr, nullptr, ff, ROWS, 4096, N_EMBD, 0, 1);
    // FF2 split-K=2 -> p0f / out (raw)
    mfma_gemm<<<dim3(N_EMBD / 128, ROWS / 128, 2), 256, 0, stream>>>(
        ff, wf2t, nullptr, nullptr, p0f, out, nullptr, ROWS, N_EMBD, 4096, 2048, 0);
    // out = p0f + out + bias + x2
    ff2_fin<<<ROWS * N_EMBD / 1024, 256, 0, stream>>>(p0f, bff2, x2, out);
}

// Round 9
// 421.219 us; speedup vs baseline: 1.1340x; 1.1340x over previous
//
#include <hip/hip_runtime.h>
#include <hip/hip_bf16.h>

#define N_EMBD 1024
#define N_HEAD 16
#define HEADSZ 64
#define BATCH  2
#define SEQ    2048
#define ROWS   (BATCH*SEQ)   /* 4096 */

typedef __attribute__((ext_vector_type(8))) short bf16x8;
typedef __attribute__((ext_vector_type(4))) float f32x4;

__device__ __forceinline__ short f2bs(float v){
    union { __hip_bfloat16 b; short s; } u; u.b = __float2bfloat16(v); return u.s;
}
__device__ __forceinline__ short scale8th(short s){   // exact: *0.125 (pow2)
    union { unsigned i; float f; } u; u.i = ((unsigned)(unsigned short)s) << 16;
    return f2bs(u.f * 0.125f);
}
__device__ __forceinline__ void gload16(const short* g, short* l){
    __builtin_amdgcn_global_load_lds(
        (const __attribute__((address_space(1))) unsigned int*)g,
        (__attribute__((address_space(3))) unsigned int*)l, 16, 0, 0);
}

// ---------------------------------------------------------------------------
// Transpose + f32->bf16 convert: out[j][i] = in[i][j]; in is [R][Cc] f32.
// ---------------------------------------------------------------------------
__global__ __launch_bounds__(256) void tr_cvt(const float* __restrict__ in,
                                              short* __restrict__ out,
                                              int R, int Cc,
                                              size_t in_z, size_t out_z)
{
    __shared__ float t[32][33];
    const int tx = threadIdx.x & 31, ty = threadIdx.x >> 5;
    const int j0 = blockIdx.x * 32, i0 = blockIdx.y * 32;
    const float* ip = in + (size_t)blockIdx.z * in_z;
    short* op = out + (size_t)blockIdx.z * out_z;
#pragma unroll
    for (int p = 0; p < 4; ++p)
        t[ty + p * 8][tx] = ip[(size_t)(i0 + ty + p * 8) * Cc + j0 + tx];
    __syncthreads();
#pragma unroll
    for (int p = 0; p < 4; ++p)
        op[(size_t)(j0 + ty + p * 8) * R + i0 + tx] = f2bs(t[tx][ty + p * 8]);
}

// Fused Wq/Wk/Wv transpose: z = which*16 + head; per-head [1024][64] -> [64][1024]
__global__ __launch_bounds__(256) void tr3_cvt(const float* __restrict__ Wq,
                                               const float* __restrict__ Wk,
                                               const float* __restrict__ Wv,
                                               short* __restrict__ w2t)
{
    __shared__ float t[32][33];
    const int tx = threadIdx.x & 31, ty = threadIdx.x >> 5;
    const int which = blockIdx.z >> 4, head = blockIdx.z & 15;
    const int j0 = blockIdx.x * 32, i0 = blockIdx.y * 32;
    const float* ip = (which == 0 ? Wq : which == 1 ? Wk : Wv) + (size_t)head * 65536;
    short* op = w2t + (size_t)which * 1048576 + (size_t)head * 65536;
#pragma unroll
    for (int p = 0; p < 4; ++p)
        t[ty + p * 8][tx] = ip[(size_t)(i0 + ty + p * 8) * 64 + j0 + tx];
    __syncthreads();
#pragma unroll
    for (int p = 0; p < 4; ++p)
        op[(size_t)(j0 + ty + p * 8) * 1024 + i0 + tx] = f2bs(t[tx][ty + p * 8]);
}

// ---------------------------------------------------------------------------
// bf16 transpose of the V slice of qkv: vt[c][token] = qkv[token][2048+c]
// ---------------------------------------------------------------------------
__global__ __launch_bounds__(256) void vt_tr(const short* __restrict__ qkv,
                                             short* __restrict__ vt)
{
    __shared__ short t[64][65];
    const int tid = threadIdx.x;
    const int sr = tid >> 2, sc = (tid & 3) * 16;
    const int col0 = blockIdx.x * 64, tok0 = blockIdx.y * 64;
    const short* ip = qkv + (size_t)(tok0 + sr) * 3072 + 2048 + col0 + sc;
    bf16x8 v0 = *(const bf16x8*)ip;
    bf16x8 v1 = *(const bf16x8*)(ip + 8);
#pragma unroll
    for (int i = 0; i < 8; ++i) { t[sr][sc + i] = v0[i]; t[sr][sc + 8 + i] = v1[i]; }
    __syncthreads();
    bf16x8 a, bq;
#pragma unroll
    for (int i = 0; i < 8; ++i) { a[i] = t[sc + i][sr]; bq[i] = t[sc + 8 + i][sr]; }
    short* op = vt + (size_t)(col0 + sr) * 4096 + tok0 + sc;
    *(bf16x8*)op = a;
    *(bf16x8*)(op + 8) = bq;
}

// ---------------------------------------------------------------------------
// LayerNorm (LN1): one block per row of 1024, float4 loads, bf16 output
// ---------------------------------------------------------------------------
__global__ __launch_bounds__(256) void ln_k(const float* __restrict__ x,
                                            const float* __restrict__ g,
                                            const float* __restrict__ bta,
                                            short* __restrict__ out)
{
    const int row = blockIdx.x;
    const int tid = threadIdx.x;
    const float* xr = x + (size_t)row * N_EMBD;
    float4 v = *(const float4*)(xr + tid * 4);
    float s  = v.x + v.y + v.z + v.w;
    float s2 = v.x * v.x + v.y * v.y + v.z * v.z + v.w * v.w;
#pragma unroll
    for (int off = 32; off; off >>= 1) {
        s  += __shfl_xor(s,  off, 64);
        s2 += __shfl_xor(s2, off, 64);
    }
    __shared__ float rs[4], rs2[4];
    const int wave = tid >> 6, lane = tid & 63;
    if (lane == 0) { rs[wave] = s; rs2[wave] = s2; }
    __syncthreads();
    s  = rs[0] + rs[1] + rs[2] + rs[3];
    s2 = rs2[0] + rs2[1] + rs2[2] + rs2[3];
    const float mean = s * (1.f / N_EMBD);
    const float var  = s2 * (1.f / N_EMBD) - mean * mean;
    const float rsig = rsqrtf(var + 1e-5f);
    float4 gv = *(const float4*)(g + tid * 4);
    float4 bv = *(const float4*)(bta + tid * 4);
    short4 o;
    o.x = f2bs((v.x - mean) * rsig * gv.x + bv.x);
    o.y = f2bs((v.y - mean) * rsig * gv.y + bv.y);
    o.z = f2bs((v.z - mean) * rsig * gv.z + bv.z);
    o.w = f2bs((v.w - mean) * rsig * gv.w + bv.w);
    *(short4*)(out + (size_t)row * N_EMBD + tid * 4) = o;
}

// ---------------------------------------------------------------------------
// Fused proj-finalize + LN2: x2 = p0+p1+bias+x (write f32); h2 = LN(x2) bf16.
// ---------------------------------------------------------------------------
__global__ __launch_bounds__(256) void pln_fin(const float* __restrict__ p0,
                                               const float* __restrict__ p1,
                                               const float* __restrict__ bias,
                                               const float* __restrict__ x,
                                               const float* __restrict__ g,
                                               const float* __restrict__ bta,
                                               float* __restrict__ x2,
                                               short* __restrict__ h2)
{
    const int row = blockIdx.x, tid = threadIdx.x;
    const size_t base = (size_t)row * N_EMBD + tid * 4;
    float4 a  = *(const float4*)(p0 + base);
    float4 c  = *(const float4*)(p1 + base);
    float4 xx = *(const float4*)(x + base);
    float4 bb = *(const float4*)(bias + tid * 4);
    float4 v;
    v.x = a.x + c.x + xx.x + bb.x;
    v.y = a.y + c.y + xx.y + bb.y;
    v.z = a.z + c.z + xx.z + bb.z;
    v.w = a.w + c.w + xx.w + bb.w;
    *(float4*)(x2 + base) = v;
    float s  = v.x + v.y + v.z + v.w;
    float s2 = v.x * v.x + v.y * v.y + v.z * v.z + v.w * v.w;
#pragma unroll
    for (int off = 32; off; off >>= 1) {
        s  += __shfl_xor(s,  off, 64);
        s2 += __shfl_xor(s2, off, 64);
    }
    __shared__ float rs[4], rs2[4];
    const int wave = tid >> 6, lane = tid & 63;
    if (lane == 0) { rs[wave] = s; rs2[wave] = s2; }
    __syncthreads();
    s  = rs[0] + rs[1] + rs[2] + rs[3];
    s2 = rs2[0] + rs2[1] + rs2[2] + rs2[3];
    const float mean = s * (1.f / N_EMBD);
    const float var  = s2 * (1.f / N_EMBD) - mean * mean;
    const float rsig = rsqrtf(var + 1e-5f);
    float4 gv = *(const float4*)(g + tid * 4);
    float4 bv = *(const float4*)(bta + tid * 4);
    short4 o;
    o.x = f2bs((v.x - mean) * rsig * gv.x + bv.x);
    o.y = f2bs((v.y - mean) * rsig * gv.y + bv.y);
    o.z = f2bs((v.z - mean) * rsig * gv.z + bv.z);
    o.w = f2bs((v.w - mean) * rsig * gv.w + bv.w);
    *(short4*)(h2 + base) = o;
}

// ---------------------------------------------------------------------------
// MFMA GEMM, bank-conflict-swizzled LDS (chunk c of row r at c^((r>>1)&3)).
// Split-K via kz (z picks outf/outf2, raw partials).
// ---------------------------------------------------------------------------
__global__ __launch_bounds__(256) void mfma_gemm(
    const short* __restrict__ A,    // [M][K] bf16
    const short* __restrict__ Bt,   // [N][K] bf16
    const float* __restrict__ bias,
    const float* __restrict__ resid,
    float* __restrict__ outf,
    float* __restrict__ outf2,
    short* __restrict__ outb,
    int M, int N, int K, int kz, int relu)
{
    __shared__ __align__(16) short As[128 * 32];
    __shared__ __align__(16) short Bs[128 * 32];
    const int tid  = threadIdx.x;
    const int lane = tid & 63, w = tid >> 6;
    const int quad = lane >> 4, l16 = lane & 15;
    const int row0 = blockIdx.y * 128, col0 = blockIdx.x * 128;
    const int wm = (w >> 1) * 64, wn = (w & 1) * 64;
    const int koff = blockIdx.z * kz;
    const int kend = kz ? kz : K;

    f32x4 acc[4][4];
#pragma unroll
    for (int i = 0; i < 4; ++i)
#pragma unroll
        for (int j = 0; j < 4; ++j)
            acc[i][j] = f32x4{0.f, 0.f, 0.f, 0.f};

    const int c0  = w * 128 + lane;
    const int c1  = c0 + 64;
    const int ar0 = c0 >> 2, ak0 = (((c0 & 3) ^ ((ar0 >> 1) & 3))) * 8; // swizzled
    const int ar1 = c1 >> 2, ak1 = (((c1 & 3) ^ ((ar1 >> 1) & 3))) * 8;
    const short* aG0 = A  + (size_t)(row0 + ar0) * K + koff + ak0;
    const short* aG1 = A  + (size_t)(row0 + ar1) * K + koff + ak1;
    const short* bG0 = Bt + (size_t)(col0 + ar0) * K + koff + ak0;
    const short* bG1 = Bt + (size_t)(col0 + ar1) * K + koff + ak1;
    short* aL0 = As + (size_t)w * 1024;
    short* aL1 = aL0 + 512;
    short* bL0 = Bs + (size_t)w * 1024;
    short* bL1 = bL0 + 512;

    const int gsw = (quad ^ ((l16 >> 1) & 3)) * 8;   // swizzled frag chunk

    for (int k0 = 0; k0 < kend; k0 += 32) {
        __syncthreads();
        gload16(aG0 + k0, aL0);
        gload16(aG1 + k0, aL1);
        gload16(bG0 + k0, bL0);
        gload16(bG1 + k0, bL1);
        asm volatile("s_waitcnt vmcnt(0)" ::: "memory");
        __syncthreads();

        bf16x8 af[4], bfr[4];
#pragma unroll
        for (int i = 0; i < 4; ++i)
            af[i]  = *(const bf16x8*)(As + (wm + i * 16 + l16) * 32 + gsw);
#pragma unroll
        for (int j = 0; j < 4; ++j)
            bfr[j] = *(const bf16x8*)(Bs + (wn + j * 16 + l16) * 32 + gsw);
#pragma unroll
        for (int i = 0; i < 4; ++i)
#pragma unroll
            for (int j = 0; j < 4; ++j)
                acc[i][j] = __builtin_amdgcn_mfma_f32_16x16x32_bf16(
                    af[i], bfr[j], acc[i][j], 0, 0, 0);
    }

    float* of = blockIdx.z ? outf2 : outf;
#pragma unroll
    for (int i = 0; i < 4; ++i) {
        const int rbase = row0 + wm + i * 16 + quad * 4;
#pragma unroll
        for (int j = 0; j < 4; ++j) {
            const int c = col0 + wn + j * 16 + l16;
            const float bv = bias ? bias[c] : 0.f;
#pragma unroll
            for (int r = 0; r < 4; ++r) {
                float v = acc[i][j][r] + bv;
                if (relu) v = fmaxf(v, 0.f);
                const size_t idx = (size_t)(rbase + r) * N + c;
                if (resid) v += resid[idx];
                if (outb) outb[idx] = f2bs(v);
                else      of[idx] = v;
            }
        }
    }
}

// ---------------------------------------------------------------------------
// FF2 finalize: out = p0 + out + bias + x2   (all f32, N=1024 bias period)
// ---------------------------------------------------------------------------
__global__ __launch_bounds__(256) void ff2_fin(const float* __restrict__ p0,
                                               const float* __restrict__ bias,
                                               const float* __restrict__ x2,
                                               float* __restrict__ out)
{
    const size_t i = ((size_t)blockIdx.x * 256 + threadIdx.x) * 4;
    float4 a = *(const float4*)(p0 + i);
    float4 b = *(const float4*)(out + i);
    float4 r = *(const float4*)(x2 + i);
    float4 bb = *(const float4*)(bias + (i & 1023));
    float4 o;
    o.x = a.x + b.x + r.x + bb.x;
    o.y = a.y + b.y + r.y + bb.y;
    o.z = a.z + b.z + r.z + bb.z;
    o.w = a.w + b.w + r.w + bb.w;
    *(float4*)(out + i) = o;
}

// ---------------------------------------------------------------------------
// MFMA flash attention: 4 waves / 64 q-rows, K/V double-buffered with 1-tile
// prefetch, ONE barrier per tile, XOR-swizzled LDS (conflict-free b128).
// grid.x = 16: pass pair {bx, 31-bx} -> each q-tile computed EXACTLY ONCE,
// uniform 33 key-tiles/block (R8 had grid.x=32 -> every tile done twice).
// ---------------------------------------------------------------------------
__global__ __launch_bounds__(256) void attn_k(const short* __restrict__ qkv,
                                              const short* __restrict__ vt,
                                              short* __restrict__ att)
{
    __shared__ __align__(16) short Ks[2][64 * 64];   // [s][d] swizzled
    __shared__ __align__(16) short Vs[2][64 * 64];   // [d][s] swizzled
    __shared__ __align__(16) short Ps[64 * 72];      // [q][s], stride 72
    const int tid  = threadIdx.x;
    const int lane = tid & 63, w = tid >> 6;         // w in 0..3
    const int quad = lane >> 4, l16 = lane & 15;
    const int bh = blockIdx.y, b = bh >> 4, head = bh & 15;

    const int srow = lane >> 3;                       // 0..7
    const int sw   = ((lane & 7) ^ srow) * 8;         // staging swizzle (shorts)
    const int cidx = (quad ^ (l16 & 7)) * 8;          // frag-read swizzle

#pragma unroll
    for (int pass = 0; pass < 2; ++pass) {
        const int qt = pass == 0 ? (int)blockIdx.x : 31 - (int)blockIdx.x;
        const int t0 = qt * 64;
        const int ntiles = qt + 1;

        // Q fragments (registers), scale folded in (exact pow2)
        const short* qp = qkv + (size_t)(b * SEQ + t0 + w * 16 + l16) * 3072
                          + head * 64 + quad * 8;
        bf16x8 qf0 = *(const bf16x8*)qp;
        bf16x8 qf1 = *(const bf16x8*)(qp + 32);
#pragma unroll
        for (int i = 0; i < 8; ++i) { qf0[i] = scale8th(qf0[i]); qf1[i] = scale8th(qf1[i]); }

        float mrow[4], lrow[4];
        f32x4 O[4];
#pragma unroll
        for (int r = 0; r < 4; ++r) { mrow[r] = -INFINITY; lrow[r] = 0.f; }
#pragma unroll
        for (int jn = 0; jn < 4; ++jn) O[jn] = f32x4{0.f, 0.f, 0.f, 0.f};

        // guard: previous pass fully done before overwriting buf0
        asm volatile("s_waitcnt vmcnt(0) lgkmcnt(0)\n\ts_barrier" ::: "memory");
        {   // prefetch tile 0 -> buffer 0 (wave w: K rows / V d-rows [w*16,+16))
            const short* kg = qkv + (size_t)(b * SEQ + w * 16 + srow) * 3072
                              + 1024 + head * 64 + sw;
            const short* vg = vt + (size_t)(head * 64 + w * 16 + srow) * 4096
                              + b * SEQ + sw;
            short* kL = Ks[0] + w * 1024;
            short* vL = Vs[0] + w * 1024;
            gload16(kg, kL); gload16(kg + (size_t)8 * 3072, kL + 512);
            gload16(vg, vL); gload16(vg + (size_t)8 * 4096, vL + 512);
        }

        for (int kt = 0; kt < ntiles; ++kt) {
            const int cur = kt & 1;
            // prefetched tile kt landed (all waves), prev compute done
            asm volatile("s_waitcnt vmcnt(0) lgkmcnt(0)\n\ts_barrier" ::: "memory");
            if (kt + 1 < ntiles) {
                const int s1 = (kt + 1) * 64;
                const short* kg = qkv + (size_t)(b * SEQ + s1 + w * 16 + srow) * 3072
                                  + 1024 + head * 64 + sw;
                const short* vg = vt + (size_t)(head * 64 + w * 16 + srow) * 4096
                                  + b * SEQ + s1 + sw;
                short* kL = Ks[cur ^ 1] + w * 1024;
                short* vL = Vs[cur ^ 1] + w * 1024;
                gload16(kg, kL); gload16(kg + (size_t)8 * 3072, kL + 512);
                gload16(vg, vL); gload16(vg + (size_t)8 * 4096, vL + 512);
            }

            // --- S = Q.K^T ---
            f32x4 S[4];
            const short* Kb = Ks[cur];
#pragma unroll
            for (int jn = 0; jn < 4; ++jn) {
                S[jn] = f32x4{0.f, 0.f, 0.f, 0.f};
                const short* kp = Kb + (jn * 16 + l16) * 64;
                bf16x8 b0 = *(const bf16x8*)(kp + cidx);
                bf16x8 b1 = *(const bf16x8*)(kp + (cidx ^ 32));
                S[jn] = __builtin_amdgcn_mfma_f32_16x16x32_bf16(qf0, b0, S[jn], 0, 0, 0);
                S[jn] = __builtin_amdgcn_mfma_f32_16x16x32_bf16(qf1, b1, S[jn], 0, 0, 0);
            }

            // --- softmax (C/D layout: row=quad*4+r, col=jn*16+l16) ---
            float Sv[4][4];
            const int tq = t0 + w * 16 + quad * 4;
            const int s0 = kt * 64;
#pragma unroll
            for (int jn = 0; jn < 4; ++jn)
#pragma unroll
                for (int r = 0; r < 4; ++r)
                    Sv[jn][r] = S[jn][r];
            if (kt == ntiles - 1) {   // diagonal tile
#pragma unroll
                for (int jn = 0; jn < 4; ++jn)
#pragma unroll
                    for (int r = 0; r < 4; ++r)
                        if (s0 + jn * 16 + l16 > tq + r) Sv[jn][r] = -INFINITY;
            }
#pragma unroll
            for (int r = 0; r < 4; ++r) {
                float rm = fmaxf(fmaxf(Sv[0][r], Sv[1][r]), fmaxf(Sv[2][r], Sv[3][r]));
#pragma unroll
                for (int off = 8; off; off >>= 1) rm = fmaxf(rm, __shfl_xor(rm, off, 64));
                const float mn    = fmaxf(mrow[r], rm);
                const float alpha = __expf(mrow[r] - mn);   // 0 on first tile
                float ps = 0.f;
#pragma unroll
                for (int jn = 0; jn < 4; ++jn) {
                    Sv[jn][r] = __expf(Sv[jn][r] - mn);
                    ps += Sv[jn][r];
                }
#pragma unroll
                for (int off = 8; off; off >>= 1) ps += __shfl_xor(ps, off, 64);
                lrow[r] = lrow[r] * alpha + ps;
                mrow[r] = mn;
#pragma unroll
                for (int jn = 0; jn < 4; ++jn) O[jn][r] *= alpha;
            }

            // --- P -> LDS (wave-local rows; lgkm wait only) ---
#pragma unroll
            for (int jn = 0; jn < 4; ++jn)
#pragma unroll
                for (int r = 0; r < 4; ++r)
                    Ps[(w * 16 + quad * 4 + r) * 72 + jn * 16 + l16] = f2bs(Sv[jn][r]);
            asm volatile("s_waitcnt lgkmcnt(0)" ::: "memory");

            // --- O += P.V ---
            const short* pp = Ps + (w * 16 + l16) * 72 + quad * 8;
            bf16x8 pf0 = *(const bf16x8*)pp;
            bf16x8 pf1 = *(const bf16x8*)(pp + 32);
            const short* Vb = Vs[cur];
#pragma unroll
            for (int jn = 0; jn < 4; ++jn) {
                const short* vp = Vb + (jn * 16 + l16) * 64;
                bf16x8 v0 = *(const bf16x8*)(vp + cidx);
                bf16x8 v1 = *(const bf16x8*)(vp + (cidx ^ 32));
                O[jn] = __builtin_amdgcn_mfma_f32_16x16x32_bf16(pf0, v0, O[jn], 0, 0, 0);
                O[jn] = __builtin_amdgcn_mfma_f32_16x16x32_bf16(pf1, v1, O[jn], 0, 0, 0);
            }
        }

        // --- write O/l ---
#pragma unroll
        for (int r = 0; r < 4; ++r) {
            const float inv = 1.f / lrow[r];
            const size_t rowoff = (size_t)(b * SEQ + t0 + w * 16 + quad * 4 + r) * N_EMBD
                                  + head * 64 + l16;
#pragma unroll
            for (int jn = 0; jn < 4; ++jn)
                att[rowoff + jn * 16] = f2bs(O[jn][r] * inv);
        }
    }
}

// ---------------------------------------------------------------------------
extern "C" void kernel_launch(void* const* d_in, const int* in_sizes, int n_in,
                              void* d_out, int out_size, void* d_ws, size_t ws_size,
                              hipStream_t stream)
{
    const float* x     = (const float*)d_in[0];
    const float* Wq    = (const float*)d_in[1];
    const float* Wk    = (const float*)d_in[2];
    const float* Wv    = (const float*)d_in[3];
    const float* Wproj = (const float*)d_in[4];
    const float* bproj = (const float*)d_in[5];
    const float* g1    = (const float*)d_in[6];
    const float* b1    = (const float*)d_in[7];
    const float* g2    = (const float*)d_in[8];
    const float* b2    = (const float*)d_in[9];
    const float* Wff1  = (const float*)d_in[10];
    const float* bff1  = (const float*)d_in[11];
    const float* Wff2  = (const float*)d_in[12];
    const float* bff2  = (const float*)d_in[13];
    float* out = (float*)d_out;

    char* ws = (char*)d_ws;
    short* w2t  = (short*)(ws + 0);          // [3072][1024] bf16 (dead after QKV)
    short* wpt  = (short*)(ws + 6291456);    // [1024][1024] (dead after proj)
    short* wf1t = (short*)(ws + 8388608);    // [4096][1024] (dead after FF1)
    short* wf2t = (short*)(ws + 16777216);   // [1024][4096]
    short* h    = (short*)(ws + 25165824);   // [4096][1024] (=h2)
    short* qkv  = (short*)(ws + 33554432);   // [4096][3072] (dead after attn)
    short* vt   = (short*)(ws + 58720256);   // [1024][4096] (dead after attn)
    short* att  = (short*)(ws + 67108864);   // [4096][1024]
    float* x2   = (float*)(ws + 75497472);   // [4096][1024] f32
    short* h2   = h;
    float* p0p  = (float*)(ws + 33554432);   // proj partials over dead qkv/vt
    float* p1p  = (float*)(ws + 50331648);
    short* ff   = qkv;                       // [4096][4096] (p0p/p1p dead by FF1)
    float* p0f  = (float*)(ws + 0);          // FF2 partial over w2t+wpt+wf1t (dead)

    tr3_cvt<<<dim3(2, 32, 48),  256, 0, stream>>>(Wq, Wk, Wv, w2t);
    tr_cvt<<<dim3(32, 32, 1),  256, 0, stream>>>(Wproj, wpt,  1024, 1024, 0, 0);
    tr_cvt<<<dim3(128, 32, 1), 256, 0, stream>>>(Wff1, wf1t,  1024, 4096, 0, 0);
    tr_cvt<<<dim3(32, 128, 1), 256, 0, stream>>>(Wff2, wf2t,  4096, 1024, 0, 0);

    ln_k<<<ROWS, 256, 0, stream>>>(x, g1, b1, h);
    // QKV: [4096,1024] x [1024,3072] -> bf16 qkv
    mfma_gemm<<<dim3(3072 / 128, ROWS / 128), 256, 0, stream>>>(
        h, w2t, nullptr, nullptr, nullptr, nullptr, qkv, ROWS, 3072, N_EMBD, 0, 0);
    vt_tr<<<dim3(16, 64), 256, 0, stream>>>(qkv, vt);
    attn_k<<<dim3(16, BATCH * N_HEAD), 256, 0, stream>>>(qkv, vt, att);
    // proj split-K=2 -> raw partials p0p/p1p (512 blocks)
    mfma_gemm<<<dim3(N_EMBD / 128, ROWS / 128, 2), 256, 0, stream>>>(
        att, wpt, nullptr, nullptr, p0p, p1p, nullptr, ROWS, N_EMBD, N_EMBD, 512, 0);
    // fused proj-epilogue + LN2: x2 = p0p+p1p+bproj+x ; h2 = LN(x2)
    pln_fin<<<ROWS, 256, 0, stream>>>(p0p, p1p, bproj, x, g2, b2, x2, h2);
    // FF1 + bias + relu -> bf16 ff
    mfma_gemm<<<dim3(4096 / 128, ROWS / 128), 256, 0, stream>>>(
        h2, wf1t, bff1, nullptr, nullptr, nullptr, ff, ROWS, 4096, N_EMBD, 0, 1);
    // FF2 split-K=2 -> p0f / out (raw)
    mfma_gemm<<<dim3(N_EMBD / 128, ROWS / 128, 2), 256, 0, stream>>>(
        ff, wf2t, nullptr, nullptr, p0f, out, nullptr, ROWS, N_EMBD, 4096, 2048, 0);
    // out = p0f + out + bias + x2
    ff2_fin<<<ROWS * N_EMBD / 1024, 256, 0, stream>>>(p0f, bff2, x2, out);
}